// Round 7
// baseline (1664.046 us; speedup 1.0000x reference)
//
#include <hip/hip_runtime.h>
#include <hip/hip_fp16.h>

typedef _Float16 f16;
typedef __attribute__((ext_vector_type(8))) _Float16 f16x8;
typedef __attribute__((ext_vector_type(4))) _Float16 f16x4;
typedef __attribute__((ext_vector_type(4))) float f32x4;
typedef __attribute__((ext_vector_type(4))) float float4v;

// Shapes: x[512,256,256], carry0[256,256], Wi[256,768], bi[768],
//         Wh[256,768], bhn[256], Wo[256,16], bo[16] -> out[512,256,16] f32
//
// gx workspace layout (scan-fragment order, produced by K1), f16:
//   vecidx = ((t*16 + blk)*8 + w8)*6 + (gate*2 + nt2)     [w8: 8x32-col waves]
//   element = vecidx*256 + lane*4 + j
// K2 consumes with w8 = wave*2 + (nt>>1), nt2 = nt&1  (wave: 4x64-col waves).

static __device__ __forceinline__ float sigm(float x) {
  return __builtin_amdgcn_rcpf(1.0f + __expf(-x));
}
static __device__ __forceinline__ float tanh_fast(float x) {
  float e = __expf(2.0f * x);
  return 1.0f - 2.0f * __builtin_amdgcn_rcpf(e + 1.0f);
}

// ---------------- K0: transpose+convert Wi -> WiT[768][256] f16 -------------
__global__ void k_prep_wit(const float* __restrict__ Wi, f16* __restrict__ WiT) {
  int n = blockIdx.x;   // 0..767
  int k = threadIdx.x;  // 0..255
  WiT[n * 256 + k] = (f16)Wi[(size_t)k * 768 + n];
}

// ---------------- K1: gx = x @ Wi + bi  (fp16 MFMA, 128x128 tile) -----------
__global__ __launch_bounds__(256, 4) void k_gemm_gx(
    const float* __restrict__ x, const f16* __restrict__ WiT,
    const float* __restrict__ bi, f16* __restrict__ gx) {
  __shared__ f16 As[128 * 64];
  __shared__ f16 Bs[128 * 64];
  const int tid = threadIdx.x;
  const int lane = tid & 63;
  const int wave = tid >> 6;
  const int wm = wave >> 1, wn = wave & 1;
  const int m0 = blockIdx.y * 128;
  const int n0 = blockIdx.x * 128;

  f32x4 acc[4][4] = {};

  for (int ks = 0; ks < 4; ++ks) {
    const int k0 = ks * 64;
#pragma unroll
    for (int i = 0; i < 8; ++i) {
      int c = i * 256 + tid;
      int row = c >> 4, cx = c & 15;
      float4v v = *reinterpret_cast<const float4v*>(
          x + (size_t)(m0 + row) * 256 + k0 + cx * 4);
      f16x4 hv;
      hv[0] = (f16)v[0]; hv[1] = (f16)v[1]; hv[2] = (f16)v[2]; hv[3] = (f16)v[3];
      int boff = row * 128 + ((cx * 8) ^ ((row & 7) << 4));
      *reinterpret_cast<f16x4*>(reinterpret_cast<char*>(As) + boff) = hv;
    }
#pragma unroll
    for (int i = 0; i < 4; ++i) {
      int c = i * 256 + tid;
      int n = c >> 3, cx = c & 7;
      f16x8 v = *reinterpret_cast<const f16x8*>(
          WiT + (size_t)(n0 + n) * 256 + k0 + cx * 8);
      int boff = n * 128 + ((cx * 16) ^ ((n & 7) << 4));
      *reinterpret_cast<f16x8*>(reinterpret_cast<char*>(Bs) + boff) = v;
    }
    __syncthreads();
#pragma unroll
    for (int kt = 0; kt < 2; ++kt) {
      const int kb = kt * 64 + ((lane >> 4) << 4);
      f16x8 a[4], b[4];
#pragma unroll
      for (int mt = 0; mt < 4; ++mt) {
        int r = wm * 64 + mt * 16 + (lane & 15);
        a[mt] = *reinterpret_cast<const f16x8*>(
            reinterpret_cast<const char*>(As) + r * 128 + (kb ^ ((r & 7) << 4)));
      }
#pragma unroll
      for (int nt = 0; nt < 4; ++nt) {
        int r = wn * 64 + nt * 16 + (lane & 15);
        b[nt] = *reinterpret_cast<const f16x8*>(
            reinterpret_cast<const char*>(Bs) + r * 128 + (kb ^ ((r & 7) << 4)));
      }
#pragma unroll
      for (int mt = 0; mt < 4; ++mt)
#pragma unroll
        for (int nt = 0; nt < 4; ++nt)
          acc[mt][nt] = __builtin_amdgcn_mfma_f32_16x16x32_f16(
              a[mt], b[nt], acc[mt][nt], 0, 0, 0);
    }
    __syncthreads();
  }
  const int t_  = blockIdx.y >> 1;
  const int bhf = blockIdx.y & 1;
  const int gg  = blockIdx.x >> 1;
  const int xh  = blockIdx.x & 1;
  float biv[4];
#pragma unroll
  for (int nt = 0; nt < 4; ++nt) biv[nt] = bi[n0 + wn * 64 + nt * 16 + (lane & 15)];
#pragma unroll
  for (int mt = 0; mt < 4; ++mt) {
    const int blk = bhf * 8 + wm * 4 + mt;
#pragma unroll
    for (int nt = 0; nt < 4; ++nt) {
      const int w = xh * 4 + wn * 2 + (nt >> 1);
      const int vecidx = ((t_ * 16 + blk) * 8 + w) * 6 + gg * 2 + (nt & 1);
      f16x4 hv;
#pragma unroll
      for (int r = 0; r < 4; ++r) hv[r] = (f16)(acc[mt][nt][r] + biv[nt]);
      *reinterpret_cast<f16x4*>(gx + (size_t)vecidx * 256 + lane * 4) = hv;
    }
  }
}

// ---------------- K2: GRU scan + batched head, 16 blocks x 4 waves ----------
// 1 wave/SIMD, __launch_bounds__(256,1) -> 512-reg unified VGPR/AGPR budget.
// Wh r,z (all cols) + n (nt 0..2) in registers (352 regs); n nt=3 slice in
// LDS. h kept as MFMA A-frags in an 8-slot LDS ring (granule swizzle
// p=g^(g>>3), conflict-free). Heads batched every 8 steps: all 4 waves
// process 2 timesteps each from the ring. gx staged-prefetched (r/z reloaded
// right after C-init; n right after elementwise). Light barrier only.
__global__ __launch_bounds__(256, 1) void k_scan(
    const float* __restrict__ carry0, const float* __restrict__ Wh,
    const float* __restrict__ bhn, const f16* __restrict__ gxL,
    const float* __restrict__ Wo, const float* __restrict__ bo,
    float* __restrict__ out) {
  __shared__ f16 ha[8 * 4096];   // 64 KB: h ring, 8 slots x (16x256 f16)
  __shared__ f16 wofs[4096];     // 8 KB: Wo B-frags (8 kt-frames)
  __shared__ f16 nfr3[16384];    // 32 KB: n-gate nt=3 B-frags, per wave
  const int tid = threadIdx.x;
  const int lane = tid & 63;
  const int wave = tid >> 6;  // 0..3
  const int l15 = lane & 15, l4 = lane >> 4;
  const int r0 = blockIdx.x * 16;

  // r,z gates, all 4 nt (16-col groups) -> 256 regs
  f16x8 whrz[2][4][8];
#pragma unroll
  for (int g = 0; g < 2; ++g)
#pragma unroll
    for (int nt = 0; nt < 4; ++nt) {
      const int col = g * 256 + wave * 64 + nt * 16 + l15;
#pragma unroll
      for (int kt = 0; kt < 8; ++kt)
#pragma unroll
        for (int e = 0; e < 8; ++e)
          whrz[g][nt][kt][e] = (f16)Wh[(size_t)(kt * 32 + l4 * 8 + e) * 768 + col];
    }
  // n gate nt=0..2 -> 96 regs
  f16x8 whn[3][8];
#pragma unroll
  for (int nt = 0; nt < 3; ++nt) {
    const int col = 512 + wave * 64 + nt * 16 + l15;
#pragma unroll
    for (int kt = 0; kt < 8; ++kt)
#pragma unroll
      for (int e = 0; e < 8; ++e)
        whn[nt][kt][e] = (f16)Wh[(size_t)(kt * 32 + l4 * 8 + e) * 768 + col];
  }
  // n gate nt=3 -> LDS frags (frag-linear, conflict-free b128)
  {
    const int col = 512 + wave * 64 + 48 + l15;
#pragma unroll
    for (int kt = 0; kt < 8; ++kt) {
      f16x8 v;
#pragma unroll
      for (int e = 0; e < 8; ++e)
        v[e] = (f16)Wh[(size_t)(kt * 32 + l4 * 8 + e) * 768 + col];
      *reinterpret_cast<f16x8*>(reinterpret_cast<char*>(nfr3) + wave * 8192 +
                                kt * 1024 + lane * 16) = v;
    }
  }
  // Wo -> LDS B-frags; wave builds frames kt=wave*2, wave*2+1
#pragma unroll
  for (int i = 0; i < 2; ++i) {
    const int kt = wave * 2 + i;
    f16x8 v;
#pragma unroll
    for (int e = 0; e < 8; ++e)
      v[e] = (f16)Wo[(kt * 32 + l4 * 8 + e) * 16 + l15];
    *reinterpret_cast<f16x8*>(reinterpret_cast<char*>(wofs) + kt * 1024 +
                              lane * 16) = v;
  }
  float bh[4];
#pragma unroll
  for (int nt = 0; nt < 4; ++nt) bh[nt] = bhn[wave * 64 + nt * 16 + l15];
  const float bov = bo[l15];

  // init h_0 -> hcur regs + ring slot 0
  float hcur[4][4];
#pragma unroll
  for (int nt = 0; nt < 4; ++nt) {
    const int f = wave * 2 + (nt >> 1);
    const int s = (nt & 1) * 2 + (l15 >> 3);
#pragma unroll
    for (int j = 0; j < 4; ++j) {
      const int row = l4 * 4 + j;
      const int col = wave * 64 + nt * 16 + l15;
      float h = carry0[(size_t)(r0 + row) * 256 + col];
      hcur[nt][j] = h;
      const int gl = s * 16 + row;
      const int p = gl ^ (gl >> 3);
      *reinterpret_cast<f16*>(reinterpret_cast<char*>(ha) + f * 1024 + p * 16 +
                              (l15 & 7) * 2) = (f16)h;
    }
  }
  __syncthreads();

  const int rdoff = (lane ^ (lane >> 3)) * 16;  // swizzled A-frag read offset

  // gx addressing: element offset for (g, nt) from per-t base
#define GOFF(g, nt) ((((nt) >> 1) * 6 + (g) * 2 + ((nt) & 1)) * 256)
  const f16* gpt = gxL + ((size_t)blockIdx.x * 8 + wave * 2) * 1536 + lane * 4;

  f16x4 gvrz[8];  // [g*4+nt] for g=0,1
  f16x4 gvn[4];
#pragma unroll
  for (int g = 0; g < 2; ++g)
#pragma unroll
    for (int nt = 0; nt < 4; ++nt)
      gvrz[g * 4 + nt] = *reinterpret_cast<const f16x4*>(gpt + GOFF(g, nt));
#pragma unroll
  for (int nt = 0; nt < 4; ++nt)
    gvn[nt] = *reinterpret_cast<const f16x4*>(gpt + GOFF(2, nt));

  // head for one timestep tau (h_tau in ring slot tau&7) -> out[tau-1]
  auto head_tau = [&](int tau) {
    const int sbase = (tau & 7) * 8192;
    f32x4 aco = {};
#pragma unroll
    for (int kt = 0; kt < 8; ++kt) {
      f16x8 a = *reinterpret_cast<const f16x8*>(
          reinterpret_cast<const char*>(ha) + sbase + kt * 1024 + rdoff);
      f16x8 wb = *reinterpret_cast<const f16x8*>(
          reinterpret_cast<const char*>(wofs) + kt * 1024 + lane * 16);
      aco = __builtin_amdgcn_mfma_f32_16x16x32_f16(a, wb, aco, 0, 0, 0);
    }
#pragma unroll
    for (int r = 0; r < 4; ++r) {
      float y = aco[r] + bov;
      if (l15 >= 8) y = __expf(fminf(fmaxf(y, -20.0f), 2.0f));
      out[((size_t)(tau - 1) * 256 + r0 + l4 * 4 + r) * 16 + l15] = y;
    }
  };

  for (int t = 0; t < 512; ++t) {
    // batched heads: at t=8k process h_{t-7}..h_t (2 per wave)
    if ((t & 7) == 0 && t > 0) {
      head_tau(t - 7 + wave * 2);
      head_tau(t - 7 + wave * 2 + 1);
      asm volatile("s_waitcnt lgkmcnt(0)\n\ts_barrier" ::: "memory");
    }
    const int cur = (t & 7) * 8192;
    const int nxt = ((t + 1) & 7) * 8192;
    const f16* gnx = gpt + (size_t)(t < 511 ? t + 1 : t) * 196608;

    // C-init: r,z from gx; n from bhn  (gvrz dies here)
    f32x4 acc[3][4];
#pragma unroll
    for (int nt = 0; nt < 4; ++nt)
#pragma unroll
      for (int j = 0; j < 4; ++j) {
        acc[0][nt][j] = (float)gvrz[nt][j];
        acc[1][nt][j] = (float)gvrz[4 + nt][j];
        acc[2][nt][j] = bh[nt];
      }
    // staged prefetch of next r/z (in flight across the whole MFMA section)
#pragma unroll
    for (int g = 0; g < 2; ++g)
#pragma unroll
      for (int nt = 0; nt < 4; ++nt)
        gvrz[g * 4 + nt] = *reinterpret_cast<const f16x4*>(gnx + GOFF(g, nt));

    // h A-frags once, reused by all 3 gate chains
    f16x8 a[8];
#pragma unroll
    for (int kt = 0; kt < 8; ++kt)
      a[kt] = *reinterpret_cast<const f16x8*>(
          reinterpret_cast<const char*>(ha) + cur + kt * 1024 + rdoff);

    // gate-major MFMA: r chain, z chain, then n chain (sigm(r/z) can
    // interleave under the n chain's issue)
#pragma unroll
    for (int kt = 0; kt < 8; ++kt)
#pragma unroll
      for (int nt = 0; nt < 4; ++nt)
        acc[0][nt] = __builtin_amdgcn_mfma_f32_16x16x32_f16(a[kt], whrz[0][nt][kt],
                                                            acc[0][nt], 0, 0, 0);
#pragma unroll
    for (int kt = 0; kt < 8; ++kt)
#pragma unroll
      for (int nt = 0; nt < 4; ++nt)
        acc[1][nt] = __builtin_amdgcn_mfma_f32_16x16x32_f16(a[kt], whrz[1][nt][kt],
                                                            acc[1][nt], 0, 0, 0);
#pragma unroll
    for (int kt = 0; kt < 8; ++kt) {
#pragma unroll
      for (int nt = 0; nt < 3; ++nt)
        acc[2][nt] = __builtin_amdgcn_mfma_f32_16x16x32_f16(a[kt], whn[nt][kt],
                                                            acc[2][nt], 0, 0, 0);
      f16x8 nb = *reinterpret_cast<const f16x8*>(
          reinterpret_cast<const char*>(nfr3) + wave * 8192 + kt * 1024 + lane * 16);
      acc[2][3] = __builtin_amdgcn_mfma_f32_16x16x32_f16(a[kt], nb, acc[2][3],
                                                         0, 0, 0);
    }

    // elementwise GRU + ring write of h_{t+1}
#pragma unroll
    for (int nt = 0; nt < 4; ++nt) {
      const int f = wave * 2 + (nt >> 1);
      const int s = (nt & 1) * 2 + (l15 >> 3);
#pragma unroll
      for (int j = 0; j < 4; ++j) {
        const int row = l4 * 4 + j;
        float rg = sigm(acc[0][nt][j]);
        float zg = sigm(acc[1][nt][j]);
        float ng = tanh_fast((float)gvn[nt][j] + rg * acc[2][nt][j]);
        float h = ng + zg * (hcur[nt][j] - ng);
        hcur[nt][j] = h;
        const int gl = s * 16 + row;
        const int p = gl ^ (gl >> 3);
        *reinterpret_cast<f16*>(reinterpret_cast<char*>(ha) + nxt + f * 1024 +
                                p * 16 + (l15 & 7) * 2) = (f16)h;
      }
    }
    // staged prefetch of next n-gate gx
#pragma unroll
    for (int nt = 0; nt < 4; ++nt)
      gvn[nt] = *reinterpret_cast<const f16x4*>(gnx + GOFF(2, nt));

    // light barrier: order the LDS h-handoff only (vmcnt stays in flight)
    asm volatile("s_waitcnt lgkmcnt(0)\n\ts_barrier" ::: "memory");
  }
#undef GOFF

  // final head batch: h_505..h_512 -> out[504..511]
  head_tau(505 + wave * 2);
  head_tau(505 + wave * 2 + 1);
}

extern "C" void kernel_launch(void* const* d_in, const int* in_sizes, int n_in,
                              void* d_out, int out_size, void* d_ws, size_t ws_size,
                              hipStream_t stream) {
  const float* x      = (const float*)d_in[0];
  const float* carry0 = (const float*)d_in[1];
  const float* Wi     = (const float*)d_in[2];
  const float* bi     = (const float*)d_in[3];
  const float* Wh     = (const float*)d_in[4];
  const float* bhn    = (const float*)d_in[5];
  const float* Wo     = (const float*)d_in[6];
  const float* bo     = (const float*)d_in[7];
  float* out = (float*)d_out;

  f16* gx  = (f16*)d_ws;                       // 512*256*768 f16 = 192 MiB
  f16* WiT = gx + (size_t)512 * 256 * 768;     // 768*256 f16

  k_prep_wit<<<dim3(768), dim3(256), 0, stream>>>(Wi, WiT);
  k_gemm_gx<<<dim3(6, 1024), dim3(256), 0, stream>>>(x, WiT, bi, gx);
  k_scan<<<dim3(16), dim3(256), 0, stream>>>(carry0, Wh, bhn, gx, Wo, bo, out);
}